// Round 1
// 549.710 us; speedup vs baseline: 1.4155x; 1.4155x over previous
//
#include <hip/hip_runtime.h>

#define B_ 16
#define T_ 1024
#define S_ 1024
#define D_ 768      // ENC == DEC
#define K3_ 1536    // D_ + D_
#define BS_ (B_ * S_)   // 16384
#define BD_ (B_ * D_)   // 12288
#define BPAD_ 40        // bf16/f16 LDS row stride: 32 k + 8 pad (80 B, 16B-aligned)

typedef __attribute__((ext_vector_type(8))) short short8;
typedef __attribute__((ext_vector_type(8))) _Float16 half8;
typedef __attribute__((ext_vector_type(4))) float float4v;

// fp32 -> bf16 (RNE)
__device__ __forceinline__ unsigned short f2bf(float x) {
    unsigned u = __builtin_bit_cast(unsigned, x);
    unsigned r = (u + 0x7fff + ((u >> 16) & 1)) >> 16;
    return (unsigned short)r;
}
// pack two fp32 -> bf16x2 in a u32 (lo=a, hi=b)
__device__ __forceinline__ unsigned pk2(float a, float b) {
    return (unsigned)f2bf(a) | ((unsigned)f2bf(b) << 16);
}
__device__ __forceinline__ uint4 cvt8(const float4 a, const float4 b) {
    return make_uint4(pk2(a.x, a.y), pk2(a.z, a.w), pk2(b.x, b.y), pk2(b.z, b.w));
}

// ---- split-fp16 helpers (Dekker 2-term split: x = hi + lo, both f16) ----
__device__ __forceinline__ void split2(float x, float y, unsigned& h, unsigned& l) {
    _Float16 hx = (_Float16)x, hy = (_Float16)y;
    float rx = x - (float)hx;           // exact in fp32
    float ry = y - (float)hy;
    _Float16 lx = (_Float16)rx, ly = (_Float16)ry;
    h = (unsigned)__builtin_bit_cast(unsigned short, hx) |
        ((unsigned)__builtin_bit_cast(unsigned short, hy) << 16);
    l = (unsigned)__builtin_bit_cast(unsigned short, lx) |
        ((unsigned)__builtin_bit_cast(unsigned short, ly) << 16);
}
__device__ __forceinline__ void split8(const float4 a, const float4 b,
                                       uint4& h, uint4& l) {
    unsigned h0, h1, h2, h3, l0, l1, l2, l3;
    split2(a.x, a.y, h0, l0);
    split2(a.z, a.w, h1, l1);
    split2(b.x, b.y, h2, l2);
    split2(b.z, b.w, h3, l3);
    h = make_uint4(h0, h1, h2, h3);
    l = make_uint4(l0, l1, l2, l3);
}

// ===========================================================================
// MFMA GEMM common: 128x128 block, 4 waves (2x2), wave=64x64 of 16x16x32
// LDS rows are k-contiguous with BPAD_ stride.
// ===========================================================================
#define MFMA_PROLOG() \
    const int tid  = threadIdx.x; \
    const int w    = tid >> 6; \
    const int wm   = (w >> 1) * 64; \
    const int wn   = (w & 1) * 64; \
    const int lane = tid & 63; \
    const int q    = lane >> 4; \
    const int lr   = lane & 15; \
    const int arow = tid >> 1; \
    const int acg  = (tid & 1) * 16; \
    float4v acc[4][4] = {};

#define MFMA_COMPUTE() \
    { \
        short8 afr[4], bfr[4]; \
        _Pragma("unroll") \
        for (int i = 0; i < 4; i++) \
            afr[i] = *(const short8*)&As[(wm + i * 16 + lr) * BPAD_ + q * 8]; \
        _Pragma("unroll") \
        for (int j = 0; j < 4; j++) \
            bfr[j] = *(const short8*)&Bs[(wn + j * 16 + lr) * BPAD_ + q * 8]; \
        _Pragma("unroll") \
        for (int i = 0; i < 4; i++) \
            _Pragma("unroll") \
            for (int j = 0; j < 4; j++) \
                acc[i][j] = __builtin_amdgcn_mfma_f32_16x16x32_bf16( \
                    afr[i], bfr[j], acc[i][j], 0, 0, 0); \
    }

// ===========================================================================
// GEMM1 (split-fp16 MFMA): scores = inputs @ ctx^T -> out2 [T,B,S]
// A-operand = ctx rows (M = s), B-operand = inp rows (N = t) so that the
// accumulator's 4 regs hold 4 consecutive s -> float4 stores on out2.
// acc = Ah*Bh + Al*Bh + Ah*Bl  (Dekker split, ~fp32 accuracy)
// ===========================================================================
__global__ __launch_bounds__(256) void gemm_scores_mfma(
    const float* __restrict__ inp, const float* __restrict__ ctx,
    float* __restrict__ out2)
{
    const int b  = blockIdx.z;
    const int t0 = blockIdx.y * 128;
    const int s0 = blockIdx.x * 128;

    __shared__ __align__(16) unsigned short Ah[128 * BPAD_];
    __shared__ __align__(16) unsigned short Al[128 * BPAD_];
    __shared__ __align__(16) unsigned short Bh[128 * BPAD_];
    __shared__ __align__(16) unsigned short Bl[128 * BPAD_];

    MFMA_PROLOG();

    const float* asrc = ctx + ((size_t)b * S_ + s0 + arow) * D_;   // M = s
    const float* bsrc = inp + ((size_t)b * T_ + t0 + arow) * D_;   // N = t

    for (int kb = 0; kb < D_; kb += 32) {
        const float* ap = asrc + kb + acg;
        const float* bp = bsrc + kb + acg;
        float4 a0 = ((const float4*)ap)[0];
        float4 a1 = ((const float4*)ap)[1];
        float4 a2 = ((const float4*)ap)[2];
        float4 a3 = ((const float4*)ap)[3];
        float4 b0 = ((const float4*)bp)[0];
        float4 b1 = ((const float4*)bp)[1];
        float4 b2 = ((const float4*)bp)[2];
        float4 b3 = ((const float4*)bp)[3];
        uint4 ah0, al0, ah1, al1, bh0, bl0, bh1, bl1;
        split8(a0, a1, ah0, al0);
        split8(a2, a3, ah1, al1);
        split8(b0, b1, bh0, bl0);
        split8(b2, b3, bh1, bl1);
        __syncthreads();
        *(uint4*)&Ah[arow * BPAD_ + acg]     = ah0;
        *(uint4*)&Ah[arow * BPAD_ + acg + 8] = ah1;
        *(uint4*)&Al[arow * BPAD_ + acg]     = al0;
        *(uint4*)&Al[arow * BPAD_ + acg + 8] = al1;
        *(uint4*)&Bh[arow * BPAD_ + acg]     = bh0;
        *(uint4*)&Bh[arow * BPAD_ + acg + 8] = bh1;
        *(uint4*)&Bl[arow * BPAD_ + acg]     = bl0;
        *(uint4*)&Bl[arow * BPAD_ + acg + 8] = bl1;
        __syncthreads();

        half8 ah[4], al4[4], bh4[4], bl4[4];
#pragma unroll
        for (int i = 0; i < 4; i++) {
            ah[i]  = *(const half8*)&Ah[(wm + i * 16 + lr) * BPAD_ + q * 8];
            al4[i] = *(const half8*)&Al[(wm + i * 16 + lr) * BPAD_ + q * 8];
        }
#pragma unroll
        for (int j = 0; j < 4; j++) {
            bh4[j] = *(const half8*)&Bh[(wn + j * 16 + lr) * BPAD_ + q * 8];
            bl4[j] = *(const half8*)&Bl[(wn + j * 16 + lr) * BPAD_ + q * 8];
        }
#pragma unroll
        for (int i = 0; i < 4; i++)
#pragma unroll
            for (int j = 0; j < 4; j++) {
                acc[i][j] = __builtin_amdgcn_mfma_f32_16x16x32_f16(
                    ah[i], bh4[j], acc[i][j], 0, 0, 0);
                acc[i][j] = __builtin_amdgcn_mfma_f32_16x16x32_f16(
                    al4[i], bh4[j], acc[i][j], 0, 0, 0);
                acc[i][j] = __builtin_amdgcn_mfma_f32_16x16x32_f16(
                    ah[i], bl4[j], acc[i][j], 0, 0, 0);
            }
    }

    // D layout: row (M=s) = q*4 + reg, col (N=t) = lr  -> float4 stores over s
#pragma unroll
    for (int i = 0; i < 4; i++)
#pragma unroll
        for (int j = 0; j < 4; j++) {
            const int t = t0 + wn + j * 16 + lr;
            const int s = s0 + wm + i * 16 + q * 4;
            *(float4v*)(out2 + (size_t)t * BS_ + (size_t)b * S_ + s) = acc[i][j];
        }
}

// ===========================================================================
// softmax / gate / scale  (unchanged)
// ===========================================================================
__global__ __launch_bounds__(256) void softmax_rows(float* __restrict__ av)
{
    const int bid = blockIdx.x;
    const int b = bid & (B_ - 1);
    const int t = bid / B_;
    float* row = av + (size_t)t * BS_ + (size_t)b * S_;
    const int tid = threadIdx.x;

    float4 v = ((float4*)row)[tid];
    float m = fmaxf(fmaxf(v.x, v.y), fmaxf(v.z, v.w));

    __shared__ float red[256];
    red[tid] = m;
    __syncthreads();
    for (int off = 128; off > 0; off >>= 1) {
        if (tid < off) red[tid] = fmaxf(red[tid], red[tid + off]);
        __syncthreads();
    }
    m = red[0];
    __syncthreads();

    float4 e;
    e.x = __expf(v.x - m); e.y = __expf(v.y - m);
    e.z = __expf(v.z - m); e.w = __expf(v.w - m);
    float s = e.x + e.y + e.z + e.w;
    red[tid] = s;
    __syncthreads();
    for (int off = 128; off > 0; off >>= 1) {
        if (tid < off) red[tid] += red[tid + off];
        __syncthreads();
    }
    const float inv = 1.0f / red[0];
    e.x *= inv; e.y *= inv; e.z *= inv; e.w *= inv;
    ((float4*)row)[tid] = e;
}

__global__ __launch_bounds__(256) void colsum_gate(
    const float* __restrict__ av, float* __restrict__ gate)
{
    const int b = blockIdx.y;
    const int s = blockIdx.x * 256 + threadIdx.x;
    const float* col = av + (size_t)b * S_ + s;
    float sum = 0.0f;
#pragma unroll 8
    for (int t = 0; t < T_; t++) sum += col[(size_t)t * BS_];
    const float g = 1.0f / (1.0f + __expf(-sum));
    gate[b * S_ + s] = g * (1.0f / (float)S_);
}

__global__ __launch_bounds__(256) void scale_av(
    float* __restrict__ av, const float* __restrict__ gate)
{
    const size_t i4 = (size_t)blockIdx.x * 256 + threadIdx.x;
    const size_t flat = i4 * 4;
    const int s = (int)(flat & (S_ - 1));
    const int b = (int)((flat >> 10) & (B_ - 1));
    float4 v = ((float4*)av)[i4];
    const float4 g = ((const float4*)gate)[(b * S_ + s) >> 2];
    v.x *= g.x; v.y *= g.y; v.z *= g.z; v.w *= g.w;
    ((float4*)av)[i4] = v;
}

// ===========================================================================
// ctx [b][s][d] fp32 -> ctxT [b][d][s] bf16  (64x64 tiles via LDS)
// ===========================================================================
__global__ __launch_bounds__(256) void transpose_ctx(
    const float* __restrict__ ctx, unsigned short* __restrict__ ctxT)
{
    const int b  = blockIdx.z;
    const int d0 = blockIdx.y * 64;
    const int s0 = blockIdx.x * 64;
    __shared__ unsigned short Ts[64 * 68];   // [d][s], stride 68 (136 B, 8B-aligned)

    const int tid = threadIdx.x;
    const int srel = tid >> 4;              // 0..15
    const int dcol = (tid & 15) * 4;        // 0..60
#pragma unroll
    for (int r = 0; r < 4; r++) {
        const int s = srel + r * 16;
        float4 v = *(const float4*)(ctx + ((size_t)b * S_ + s0 + s) * D_ + d0 + dcol);
        Ts[(dcol + 0) * 68 + s] = f2bf(v.x);
        Ts[(dcol + 1) * 68 + s] = f2bf(v.y);
        Ts[(dcol + 2) * 68 + s] = f2bf(v.z);
        Ts[(dcol + 3) * 68 + s] = f2bf(v.w);
    }
    __syncthreads();
    const int drow = tid >> 2;              // 0..63
    const int scg  = (tid & 3) * 16;        // 0..48
    unsigned short* dst = ctxT + ((size_t)b * D_ + d0 + drow) * S_ + s0 + scg;
#pragma unroll
    for (int p = 0; p < 4; p++) {
        uint2 u = *(const uint2*)&Ts[drow * 68 + scg + p * 4];
        *(uint2*)(dst + p * 4) = u;
    }
}

// ===========================================================================
// GEMM2: c_bf[b,t,d] = bf16( (av_g @ ctx) * w_scale + b_scale )
// ===========================================================================
__global__ __launch_bounds__(256) void gemm_ctx_mfma(
    const float* __restrict__ avg, const unsigned short* __restrict__ ctxT,
    const float* __restrict__ w_scale, const float* __restrict__ b_scale,
    unsigned short* __restrict__ c_bf)
{
    const int b  = blockIdx.z;
    const int t0 = blockIdx.y * 128;
    const int d0 = blockIdx.x * 128;

    __shared__ __align__(16) unsigned short As[128 * BPAD_];
    __shared__ __align__(16) unsigned short Bs[128 * BPAD_];

    MFMA_PROLOG();

    const float* asrc = avg + (size_t)(t0 + arow) * BS_ + (size_t)b * S_;
    const unsigned short* bsrc = ctxT + ((size_t)b * D_ + d0 + arow) * S_;

    for (int sb = 0; sb < S_; sb += 32) {
        const float* ap = asrc + sb + acg;
        float4 f0 = ((const float4*)ap)[0];
        float4 f1 = ((const float4*)ap)[1];
        float4 f2 = ((const float4*)ap)[2];
        float4 f3 = ((const float4*)ap)[3];
        uint4 bu0 = ((const uint4*)(bsrc + sb + acg))[0];
        uint4 bu1 = ((const uint4*)(bsrc + sb + acg))[1];
        uint4 au0 = cvt8(f0, f1);
        uint4 au1 = cvt8(f2, f3);
        __syncthreads();
        *(uint4*)&As[arow * BPAD_ + acg]     = au0;
        *(uint4*)&As[arow * BPAD_ + acg + 8] = au1;
        *(uint4*)&Bs[arow * BPAD_ + acg]     = bu0;
        *(uint4*)&Bs[arow * BPAD_ + acg + 8] = bu1;
        __syncthreads();
        MFMA_COMPUTE();
    }

    const float wsc = w_scale[0], bsc = b_scale[0];
#pragma unroll
    for (int i = 0; i < 4; i++)
#pragma unroll
    for (int j = 0; j < 4; j++) {
        const int d = d0 + wn + j * 16 + lr;
#pragma unroll
        for (int r = 0; r < 4; r++) {
            const int t = t0 + wm + i * 16 + q * 4 + r;
            c_bf[((size_t)b * T_ + t) * D_ + d] = f2bf(acc[i][j][r] * wsc + bsc);
        }
    }
}

// ===========================================================================
// GEMM3: h = prelu(concat(c_bf, inputs) @ W^T + bias) -> out0 [T,B,D]
// ===========================================================================
__global__ __launch_bounds__(256) void gemm_out_mfma(
    const unsigned short* __restrict__ c_bf, const float* __restrict__ inp,
    const float* __restrict__ W, const float* __restrict__ bias,
    const float* __restrict__ prelu_a, float* __restrict__ out0)
{
    const int n0 = blockIdx.y * 128;
    const int d0 = blockIdx.x * 128;

    __shared__ __align__(16) unsigned short As[128 * BPAD_];
    __shared__ __align__(16) unsigned short Bs[128 * BPAD_];

    MFMA_PROLOG();

    for (int kb = 0; kb < K3_; kb += 32) {
        uint4 au0, au1, bu0, bu1;
        if (kb < D_) {   // block-uniform branch
            const unsigned short* ap = c_bf + (size_t)(n0 + arow) * D_ + kb + acg;
            au0 = ((const uint4*)ap)[0];
            au1 = ((const uint4*)ap)[1];
        } else {
            const float* ap = inp + (size_t)(n0 + arow) * D_ + (kb - D_) + acg;
            float4 f0 = ((const float4*)ap)[0];
            float4 f1 = ((const float4*)ap)[1];
            float4 f2 = ((const float4*)ap)[2];
            float4 f3 = ((const float4*)ap)[3];
            au0 = cvt8(f0, f1);
            au1 = cvt8(f2, f3);
        }
        {
            const float* bp = W + (size_t)(d0 + arow) * K3_ + kb + acg;
            float4 g0 = ((const float4*)bp)[0];
            float4 g1 = ((const float4*)bp)[1];
            float4 g2 = ((const float4*)bp)[2];
            float4 g3 = ((const float4*)bp)[3];
            bu0 = cvt8(g0, g1);
            bu1 = cvt8(g2, g3);
        }
        __syncthreads();
        *(uint4*)&As[arow * BPAD_ + acg]     = au0;
        *(uint4*)&As[arow * BPAD_ + acg + 8] = au1;
        *(uint4*)&Bs[arow * BPAD_ + acg]     = bu0;
        *(uint4*)&Bs[arow * BPAD_ + acg + 8] = bu1;
        __syncthreads();
        MFMA_COMPUTE();
    }

    const float pa = prelu_a[0];
#pragma unroll
    for (int j = 0; j < 4; j++) {
        const int d = d0 + wn + j * 16 + lr;
        const float bz = bias[d];
#pragma unroll
        for (int i = 0; i < 4; i++) {
#pragma unroll
            for (int r = 0; r < 4; r++) {
                const int n = n0 + wm + i * 16 + q * 4 + r;
                const int bb = n >> 10;
                const int t = n & (T_ - 1);
                float h = acc[i][j][r] + bz;
                h = h >= 0.0f ? h : pa * h;
                out0[(size_t)t * BD_ + (size_t)bb * D_ + d] = h;
            }
        }
    }
}

// ===========================================================================
extern "C" void kernel_launch(void* const* d_in, const int* in_sizes, int n_in,
                              void* d_out, int out_size, void* d_ws, size_t ws_size,
                              hipStream_t stream)
{
    const float* inputs  = (const float*)d_in[0];   // [B,T,768]
    const float* context = (const float*)d_in[1];   // [B,S,768]
    const float* W_out   = (const float*)d_in[2];   // [768,1536]
    const float* b_out   = (const float*)d_in[3];   // [768]
    const float* w_scale = (const float*)d_in[4];
    const float* b_scale = (const float*)d_in[5];
    const float* prelu_a = (const float*)d_in[6];

    float* out0 = (float*)d_out;                          // [T,B,768]
    float* out2 = out0 + (size_t)T_ * B_ * D_;            // [T,B,S] (av_g)

    // ws: c_bf (25.2 MB) | ctxT (25.2 MB) | gate (64 KB)
    unsigned short* c_bf = (unsigned short*)d_ws;
    unsigned short* ctxT = c_bf + (size_t)B_ * T_ * D_;
    float* gate = (float*)(ctxT + (size_t)B_ * D_ * S_);

    // 0. ctx -> ctxT bf16 (independent of steps 1-4)
    transpose_ctx<<<dim3(S_ / 64, D_ / 64, B_), 256, 0, stream>>>(context, ctxT);
    // 1. scores -> out2 (split-fp16 MFMA, ~fp32 accuracy)
    gemm_scores_mfma<<<dim3(S_ / 128, T_ / 128, B_), 256, 0, stream>>>(
        inputs, context, out2);
    // 2. softmax in place
    softmax_rows<<<B_ * T_, 256, 0, stream>>>(out2);
    // 3. gate
    colsum_gate<<<dim3(S_ / 256, B_), 256, 0, stream>>>(out2, gate);
    // 4. av_g in place
    scale_av<<<(int)(((size_t)T_ * B_ * S_ / 4) / 256), 256, 0, stream>>>(out2, gate);
    // 5. c = bf16((av_g @ ctx) * ws + bs)   [MFMA]
    gemm_ctx_mfma<<<dim3(D_ / 128, T_ / 128, B_), 256, 0, stream>>>(
        out2, ctxT, w_scale, b_scale, c_bf);
    // 6. h = prelu(concat @ W^T + b) -> out0   [MFMA]
    gemm_out_mfma<<<dim3(D_ / 128, (B_ * T_) / 128), 256, 0, stream>>>(
        c_bf, inputs, W_out, b_out, prelu_a, out0);
}

// Round 2
// 439.061 us; speedup vs baseline: 1.7723x; 1.2520x over previous
//
#include <hip/hip_runtime.h>

#define B_ 16
#define T_ 1024
#define S_ 1024
#define D_ 768      // ENC == DEC
#define K3_ 1536    // D_ + D_
#define BS_ (B_ * S_)   // 16384
#define BD_ (B_ * D_)   // 12288
#define BPAD_ 40        // fp16 LDS row stride: 32 k + 8 pad (80 B, 16B-aligned)
#define NI_ (B_ * T_ * D_)      // 12582912 (inp elems)
#define NW_ (D_ * K3_)          // 1179648  (W elems)

typedef __attribute__((ext_vector_type(8))) _Float16 half8;
typedef __attribute__((ext_vector_type(4))) float float4v;

// ---- fp32 <-> fp16 helpers ----
__device__ __forceinline__ unsigned short f2h(float x) {
    return __builtin_bit_cast(unsigned short, (_Float16)x);
}
__device__ __forceinline__ float h2f(unsigned short u) {
    return (float)__builtin_bit_cast(_Float16, u);
}
__device__ __forceinline__ unsigned pkh2(float a, float b) {
    return (unsigned)f2h(a) | ((unsigned)f2h(b) << 16);
}
__device__ __forceinline__ uint2 pkh4(const float4 v) {
    return make_uint2(pkh2(v.x, v.y), pkh2(v.z, v.w));
}

// ===========================================================================
// MFMA GEMM common: 128x128 block, 4 waves (2x2), wave=64x64 of 16x16x32 f16
// LDS rows are k-contiguous (32 elems) with BPAD_ stride.
// C/D mapping (verified R1): col = lane&15 (N-operand), row = (lane>>4)*4+reg
// ===========================================================================
#define MFMA_PROLOG() \
    const int tid  = threadIdx.x; \
    const int w    = tid >> 6; \
    const int wm   = (w >> 1) * 64; \
    const int wn   = (w & 1) * 64; \
    const int lane = tid & 63; \
    const int q    = lane >> 4; \
    const int lr   = lane & 15; \
    const int arow = tid >> 1; \
    const int acg  = (tid & 1) * 16; \
    float4v acc[4][4] = {};

#define MFMA_COMPUTE_F16() \
    { \
        half8 afr[4], bfr[4]; \
        _Pragma("unroll") \
        for (int i = 0; i < 4; i++) \
            afr[i] = *(const half8*)&As[(wm + i * 16 + lr) * BPAD_ + q * 8]; \
        _Pragma("unroll") \
        for (int j = 0; j < 4; j++) \
            bfr[j] = *(const half8*)&Bs[(wn + j * 16 + lr) * BPAD_ + q * 8]; \
        _Pragma("unroll") \
        for (int i = 0; i < 4; i++) \
            _Pragma("unroll") \
            for (int j = 0; j < 4; j++) \
                acc[i][j] = __builtin_amdgcn_mfma_f32_16x16x32_f16( \
                    afr[i], bfr[j], acc[i][j], 0, 0, 0); \
    }

// ===========================================================================
// prep_h: inp (fp32) -> inp_h (fp16), W (fp32) -> W_h (fp16)
// ===========================================================================
__global__ __launch_bounds__(256) void prep_h(
    const float* __restrict__ inp, const float* __restrict__ W,
    unsigned short* __restrict__ inp_h, unsigned short* __restrict__ W_h)
{
    const size_t i4 = (size_t)blockIdx.x * 256 + threadIdx.x;
    const size_t flat = i4 * 4;
    float4 v;
    unsigned short* dst;
    if (flat < NI_) {
        v = ((const float4*)inp)[i4];
        dst = inp_h + flat;
    } else {
        v = *(const float4*)(W + (flat - NI_));
        dst = W_h + (flat - NI_);
    }
    *(uint2*)dst = pkh4(v);
}

// ===========================================================================
// transpose_ctx: ctx [b][s][d] fp32 -> ctxT [b][d][s] fp16  AND ctx_h [b][s][d] fp16
// ===========================================================================
__global__ __launch_bounds__(256) void transpose_ctx(
    const float* __restrict__ ctx, unsigned short* __restrict__ ctxT,
    unsigned short* __restrict__ ctx_h)
{
    const int b  = blockIdx.z;
    const int d0 = blockIdx.y * 64;
    const int s0 = blockIdx.x * 64;
    __shared__ unsigned short Ts[64 * 68];   // [d][s], stride 68

    const int tid = threadIdx.x;
    const int srel = tid >> 4;              // 0..15
    const int dcol = (tid & 15) * 4;        // 0..60
#pragma unroll
    for (int r = 0; r < 4; r++) {
        const int s = srel + r * 16;
        float4 v = *(const float4*)(ctx + ((size_t)b * S_ + s0 + s) * D_ + d0 + dcol);
        Ts[(dcol + 0) * 68 + s] = f2h(v.x);
        Ts[(dcol + 1) * 68 + s] = f2h(v.y);
        Ts[(dcol + 2) * 68 + s] = f2h(v.z);
        Ts[(dcol + 3) * 68 + s] = f2h(v.w);
        *(uint2*)(ctx_h + ((size_t)b * S_ + s0 + s) * D_ + d0 + dcol) = pkh4(v);
    }
    __syncthreads();
    const int drow = tid >> 2;              // 0..63
    const int scg  = (tid & 3) * 16;        // 0..48
    unsigned short* dst = ctxT + ((size_t)b * D_ + d0 + drow) * S_ + s0 + scg;
#pragma unroll
    for (int p = 0; p < 4; p++) {
        uint2 u = *(const uint2*)&Ts[drow * 68 + scg + p * 4];
        *(uint2*)(dst + p * 4) = u;
    }
}

// ===========================================================================
// GEMM1 (fp16 MFMA): scores = inputs @ ctx^T -> out2 [T,B,S] fp32
// A = ctx_h rows (M = s), B = inp_h rows (N = t); pure-copy staging.
// ===========================================================================
__global__ __launch_bounds__(256) void gemm_scores_f16(
    const unsigned short* __restrict__ ctx_h,
    const unsigned short* __restrict__ inp_h,
    float* __restrict__ out2)
{
    const int b  = blockIdx.z;
    const int t0 = blockIdx.y * 128;
    const int s0 = blockIdx.x * 128;

    __shared__ __align__(16) unsigned short As[128 * BPAD_];
    __shared__ __align__(16) unsigned short Bs[128 * BPAD_];

    MFMA_PROLOG();

    const unsigned short* asrc = ctx_h + ((size_t)b * S_ + s0 + arow) * D_;
    const unsigned short* bsrc = inp_h + ((size_t)b * T_ + t0 + arow) * D_;

    for (int kb = 0; kb < D_; kb += 32) {
        const uint4 a0 = ((const uint4*)(asrc + kb + acg))[0];
        const uint4 a1 = ((const uint4*)(asrc + kb + acg))[1];
        const uint4 b0 = ((const uint4*)(bsrc + kb + acg))[0];
        const uint4 b1 = ((const uint4*)(bsrc + kb + acg))[1];
        __syncthreads();
        *(uint4*)&As[arow * BPAD_ + acg]     = a0;
        *(uint4*)&As[arow * BPAD_ + acg + 8] = a1;
        *(uint4*)&Bs[arow * BPAD_ + acg]     = b0;
        *(uint4*)&Bs[arow * BPAD_ + acg + 8] = b1;
        __syncthreads();
        MFMA_COMPUTE_F16();
    }

#pragma unroll
    for (int i = 0; i < 4; i++)
#pragma unroll
        for (int j = 0; j < 4; j++) {
            const int t = t0 + wn + j * 16 + lr;
            const int s = s0 + wm + i * 16 + q * 4;
            *(float4v*)(out2 + (size_t)t * BS_ + (size_t)b * S_ + s) = acc[i][j];
        }
}

// ===========================================================================
// softmax_rows: out2 (scores fp32) -> av_h [t][b][s] fp16
// ===========================================================================
__global__ __launch_bounds__(256) void softmax_rows(
    const float* __restrict__ scores, unsigned short* __restrict__ av_h)
{
    const int bid = blockIdx.x;
    const int b = bid & (B_ - 1);
    const int t = bid / B_;
    const float* row = scores + (size_t)t * BS_ + (size_t)b * S_;
    const int tid = threadIdx.x;

    float4 v = ((const float4*)row)[tid];
    float m = fmaxf(fmaxf(v.x, v.y), fmaxf(v.z, v.w));
#pragma unroll
    for (int off = 32; off > 0; off >>= 1) m = fmaxf(m, __shfl_xor(m, off));

    __shared__ float red[8];
    if ((tid & 63) == 0) red[tid >> 6] = m;
    __syncthreads();
    m = fmaxf(fmaxf(red[0], red[1]), fmaxf(red[2], red[3]));

    float4 e;
    e.x = __expf(v.x - m); e.y = __expf(v.y - m);
    e.z = __expf(v.z - m); e.w = __expf(v.w - m);
    float s = e.x + e.y + e.z + e.w;
#pragma unroll
    for (int off = 32; off > 0; off >>= 1) s += __shfl_xor(s, off);
    if ((tid & 63) == 0) red[4 + (tid >> 6)] = s;
    __syncthreads();
    s = (red[4] + red[5]) + (red[6] + red[7]);

    const float inv = 1.0f / s;
    e.x *= inv; e.y *= inv; e.z *= inv; e.w *= inv;
    unsigned short* orow = av_h + (size_t)t * BS_ + (size_t)b * S_;
    *(uint2*)(orow + tid * 4) = pkh4(e);
}

// ===========================================================================
// colsum_part: partial[c][b][s] = sum over t-chunk c (128 rows) of av_h
// grid (S/512, B, T/128), 256 threads, 2 s per thread
// ===========================================================================
__global__ __launch_bounds__(256) void colsum_part(
    const unsigned short* __restrict__ av_h, float* __restrict__ partial)
{
    const int b = blockIdx.y;
    const int c = blockIdx.z;
    const int s2 = blockIdx.x * 512 + threadIdx.x * 2;
    const unsigned short* p = av_h + (size_t)(c * 128) * BS_ + (size_t)b * S_ + s2;
    float s0 = 0.0f, s1 = 0.0f;
#pragma unroll 8
    for (int t = 0; t < 128; t++) {
        const unsigned u = *(const unsigned*)(p + (size_t)t * BS_);
        s0 += h2f((unsigned short)(u & 0xffff));
        s1 += h2f((unsigned short)(u >> 16));
    }
    *(float2*)(partial + ((size_t)c * B_ + b) * S_ + s2) = make_float2(s0, s1);
}

// gate[b][s] = sigmoid(colsum) / S
__global__ __launch_bounds__(256) void gate_final(
    const float* __restrict__ partial, float* __restrict__ gate)
{
    const int idx = blockIdx.x * 256 + threadIdx.x;   // b*1024 + s
    const int b = idx >> 10, s = idx & (S_ - 1);
    float sum = 0.0f;
#pragma unroll
    for (int c = 0; c < T_ / 128; c++) sum += partial[((size_t)c * B_ + b) * S_ + s];
    gate[idx] = (1.0f / (1.0f + __expf(-sum))) * (1.0f / (float)S_);
}

// av_g (out2, fp32) = f32(av_h) * gate[b][s]
__global__ __launch_bounds__(256) void av_out(
    const unsigned short* __restrict__ av_h, const float* __restrict__ gate,
    float* __restrict__ out2)
{
    const size_t i8 = ((size_t)blockIdx.x * 256 + threadIdx.x) * 8;
    const int s = (int)(i8 & (S_ - 1));
    const int b = (int)((i8 >> 10) & (B_ - 1));
    const uint4 u = *(const uint4*)(av_h + i8);
    const float4 g0 = *(const float4*)(gate + b * S_ + s);
    const float4 g1 = *(const float4*)(gate + b * S_ + s + 4);
    float4 o0 = make_float4(h2f(u.x & 0xffff) * g0.x, h2f(u.x >> 16) * g0.y,
                            h2f(u.y & 0xffff) * g0.z, h2f(u.y >> 16) * g0.w);
    float4 o1 = make_float4(h2f(u.z & 0xffff) * g1.x, h2f(u.z >> 16) * g1.y,
                            h2f(u.w & 0xffff) * g1.z, h2f(u.w >> 16) * g1.w);
    *(float4*)(out2 + i8) = o0;
    *(float4*)(out2 + i8 + 4) = o1;
}

// ctxT[b][d][s] *= gate[b][s]  (in place) — folds gate into GEMM2's A operand
__global__ __launch_bounds__(256) void scale_ctxT(
    unsigned short* __restrict__ ctxT, const float* __restrict__ gate)
{
    const int b = blockIdx.y;
    const int d = blockIdx.x * 2 + (threadIdx.x >> 7);
    const int s = (threadIdx.x & 127) * 8;
    unsigned short* p = ctxT + ((size_t)b * D_ + d) * S_ + s;
    const uint4 u = *(const uint4*)p;
    const float4 g0 = *(const float4*)(gate + b * S_ + s);
    const float4 g1 = *(const float4*)(gate + b * S_ + s + 4);
    uint4 o;
    o.x = pkh2(h2f(u.x & 0xffff) * g0.x, h2f(u.x >> 16) * g0.y);
    o.y = pkh2(h2f(u.y & 0xffff) * g0.z, h2f(u.y >> 16) * g0.w);
    o.z = pkh2(h2f(u.z & 0xffff) * g1.x, h2f(u.z >> 16) * g1.y);
    o.w = pkh2(h2f(u.w & 0xffff) * g1.z, h2f(u.w >> 16) * g1.w);
    *(uint4*)p = o;
}

// ===========================================================================
// GEMM2 (fp16): c_h[b,t,d] = f16( (av @ ctxT_g) * w_scale + b_scale )
// A = ctxT_g rows (M = d), B = av_h rows (N = t); pure-copy staging.
// ===========================================================================
__global__ __launch_bounds__(256) void gemm_ctx_f16(
    const unsigned short* __restrict__ ctxT, const unsigned short* __restrict__ av_h,
    const float* __restrict__ w_scale, const float* __restrict__ b_scale,
    unsigned short* __restrict__ c_h)
{
    const int b  = blockIdx.z;
    const int d0 = blockIdx.y * 128;
    const int t0 = blockIdx.x * 128;

    __shared__ __align__(16) unsigned short As[128 * BPAD_];
    __shared__ __align__(16) unsigned short Bs[128 * BPAD_];

    MFMA_PROLOG();

    const unsigned short* asrc = ctxT + ((size_t)b * D_ + d0 + arow) * S_;
    const unsigned short* bsrc = av_h + (size_t)(t0 + arow) * BS_ + (size_t)b * S_;

    for (int sb = 0; sb < S_; sb += 32) {
        const uint4 a0 = ((const uint4*)(asrc + sb + acg))[0];
        const uint4 a1 = ((const uint4*)(asrc + sb + acg))[1];
        const uint4 b0 = ((const uint4*)(bsrc + sb + acg))[0];
        const uint4 b1 = ((const uint4*)(bsrc + sb + acg))[1];
        __syncthreads();
        *(uint4*)&As[arow * BPAD_ + acg]     = a0;
        *(uint4*)&As[arow * BPAD_ + acg + 8] = a1;
        *(uint4*)&Bs[arow * BPAD_ + acg]     = b0;
        *(uint4*)&Bs[arow * BPAD_ + acg + 8] = b1;
        __syncthreads();
        MFMA_COMPUTE_F16();
    }

    const float wsc = w_scale[0], bsc = b_scale[0];
#pragma unroll
    for (int i = 0; i < 4; i++)
#pragma unroll
        for (int j = 0; j < 4; j++) {
            const int d = d0 + wm + i * 16 + q * 4;
            const int t = t0 + wn + j * 16 + lr;
            uint2 o;
            o.x = pkh2(acc[i][j][0] * wsc + bsc, acc[i][j][1] * wsc + bsc);
            o.y = pkh2(acc[i][j][2] * wsc + bsc, acc[i][j][3] * wsc + bsc);
            *(uint2*)(c_h + ((size_t)b * T_ + t) * D_ + d) = o;
        }
}

// ===========================================================================
// GEMM3 (fp16): h = prelu(concat(c_h, inp_h) @ W_h^T + bias) -> out0 [T,B,D]
// A = W_h rows (M = d), B = concat rows (N = n = b*T+t); pure-copy staging.
// ===========================================================================
__global__ __launch_bounds__(256) void gemm_out_f16(
    const unsigned short* __restrict__ c_h, const unsigned short* __restrict__ inp_h,
    const unsigned short* __restrict__ W_h, const float* __restrict__ bias,
    const float* __restrict__ prelu_a, float* __restrict__ out0)
{
    const int n0 = blockIdx.x * 128;
    const int d0 = blockIdx.y * 128;

    __shared__ __align__(16) unsigned short As[128 * BPAD_];
    __shared__ __align__(16) unsigned short Bs[128 * BPAD_];

    MFMA_PROLOG();

    const unsigned short* asrc = W_h + (size_t)(d0 + arow) * K3_;

    for (int kb = 0; kb < K3_; kb += 32) {
        const uint4 a0 = ((const uint4*)(asrc + kb + acg))[0];
        const uint4 a1 = ((const uint4*)(asrc + kb + acg))[1];
        const unsigned short* bp = (kb < D_)
            ? c_h   + (size_t)(n0 + arow) * D_ + kb + acg
            : inp_h + (size_t)(n0 + arow) * D_ + (kb - D_) + acg;
        const uint4 b0 = ((const uint4*)bp)[0];
        const uint4 b1 = ((const uint4*)bp)[1];
        __syncthreads();
        *(uint4*)&As[arow * BPAD_ + acg]     = a0;
        *(uint4*)&As[arow * BPAD_ + acg + 8] = a1;
        *(uint4*)&Bs[arow * BPAD_ + acg]     = b0;
        *(uint4*)&Bs[arow * BPAD_ + acg + 8] = b1;
        __syncthreads();
        MFMA_COMPUTE_F16();
    }

    const float pa = prelu_a[0];
#pragma unroll
    for (int i = 0; i < 4; i++) {
        const int d = d0 + wm + i * 16 + q * 4;
        const float4 bz = *(const float4*)(bias + d);
#pragma unroll
        for (int j = 0; j < 4; j++) {
            const int n = n0 + wn + j * 16 + lr;
            const int bb = n >> 10;
            const int t = n & (T_ - 1);
            float4 h;
            h.x = acc[i][j][0] + bz.x;
            h.y = acc[i][j][1] + bz.y;
            h.z = acc[i][j][2] + bz.z;
            h.w = acc[i][j][3] + bz.w;
            h.x = h.x >= 0.0f ? h.x : pa * h.x;
            h.y = h.y >= 0.0f ? h.y : pa * h.y;
            h.z = h.z >= 0.0f ? h.z : pa * h.z;
            h.w = h.w >= 0.0f ? h.w : pa * h.w;
            *(float4*)(out0 + (size_t)t * BD_ + (size_t)bb * D_ + d) = h;
        }
    }
}

// ===========================================================================
extern "C" void kernel_launch(void* const* d_in, const int* in_sizes, int n_in,
                              void* d_out, int out_size, void* d_ws, size_t ws_size,
                              hipStream_t stream)
{
    const float* inputs  = (const float*)d_in[0];   // [B,T,768]
    const float* context = (const float*)d_in[1];   // [B,S,768]
    const float* W_out   = (const float*)d_in[2];   // [768,1536]
    const float* b_out   = (const float*)d_in[3];   // [768]
    const float* w_scale = (const float*)d_in[4];
    const float* b_scale = (const float*)d_in[5];
    const float* prelu_a = (const float*)d_in[6];

    float* out0 = (float*)d_out;                          // [T,B,768]
    float* out2 = out0 + (size_t)T_ * B_ * D_;            // [T,B,S] (scores -> av_g)

    // ws layout (fp16 regions then fp32 regions), ~112 MB total:
    unsigned short* c_h   = (unsigned short*)d_ws;                 // B*T*D
    unsigned short* ctxT  = c_h   + (size_t)B_ * T_ * D_;          // B*D*S
    unsigned short* av_h  = ctxT  + (size_t)B_ * D_ * S_;          // T*B*S
    unsigned short* inp_h = av_h  + (size_t)T_ * B_ * S_;          // B*T*D
    unsigned short* W_h   = inp_h + (size_t)B_ * T_ * D_;          // D*K3
    float* gate    = (float*)(W_h + (size_t)NW_);                  // B*S
    float* partial = gate + (size_t)B_ * S_;                       // 8*B*S

    // 0. fp16 precasts (independent of everything else)
    prep_h<<<(NI_ + NW_) / 4 / 256, 256, 0, stream>>>(inputs, W_out, inp_h, W_h);
    // 1. ctx -> ctxT fp16 [b][d][s] + ctx_h would alias ctxT; writes both
    transpose_ctx<<<dim3(S_ / 64, D_ / 64, B_), 256, 0, stream>>>(context, ctxT, c_h);
    // NOTE: ctx_h is staged in the c_h region (c_h written only later by gemm2,
    // after gemm1 has consumed ctx_h — lifetimes are disjoint).
    // 2. scores -> out2 (pure fp16 MFMA GEMM)
    gemm_scores_f16<<<dim3(S_ / 128, T_ / 128, B_), 256, 0, stream>>>(
        c_h /*ctx_h*/, inp_h, out2);
    // 3. softmax: out2 -> av_h (fp16)
    softmax_rows<<<B_ * T_, 256, 0, stream>>>(out2, av_h);
    // 4. column partial sums over t
    colsum_part<<<dim3(S_ / 512, B_, T_ / 128), 256, 0, stream>>>(av_h, partial);
    // 5. gate = sigmoid(colsum)/S
    gate_final<<<(B_ * S_) / 256, 256, 0, stream>>>(partial, gate);
    // 6. av_g -> out2 (final output 1)
    av_out<<<(int)(((size_t)T_ * B_ * S_ / 8) / 256), 256, 0, stream>>>(av_h, gate, out2);
    // 7. fold gate into ctxT (in place)
    scale_ctxT<<<dim3(D_ / 2, B_), 256, 0, stream>>>(ctxT, gate);
    // 8. c_h = f16((av @ ctxT_g) * ws + bs)   [fp16 MFMA]
    gemm_ctx_f16<<<dim3(T_ / 128, D_ / 128, B_), 256, 0, stream>>>(
        ctxT, av_h, w_scale, b_scale, c_h);
    // 9. h = prelu(concat @ W^T + b) -> out0   [fp16 MFMA]
    gemm_out_f16<<<dim3((B_ * T_) / 128, D_ / 128), 256, 0, stream>>>(
        c_h, inp_h, W_h, b_out, prelu_a, out0);
}

// Round 3
// 391.313 us; speedup vs baseline: 1.9885x; 1.1220x over previous
//
#include <hip/hip_runtime.h>

#define B_ 16
#define T_ 1024
#define S_ 1024
#define D_ 768      // ENC == DEC
#define K3_ 1536    // D_ + D_
#define BS_ (B_ * S_)   // 16384
#define BD_ (B_ * D_)   // 12288
#define NI_ (B_ * T_ * D_)      // 12582912 (inp elems)
#define NW_ (D_ * K3_)          // 1179648  (W elems)

typedef __attribute__((ext_vector_type(8))) _Float16 half8;
typedef __attribute__((ext_vector_type(4))) float float4v;

// ---- fp32 <-> fp16 helpers ----
__device__ __forceinline__ unsigned short f2h(float x) {
    return __builtin_bit_cast(unsigned short, (_Float16)x);
}
__device__ __forceinline__ float h2f(unsigned short u) {
    return (float)__builtin_bit_cast(_Float16, u);
}
__device__ __forceinline__ unsigned pkh2(float a, float b) {
    return (unsigned)f2h(a) | ((unsigned)f2h(b) << 16);
}
__device__ __forceinline__ uint2 pkh4(const float4 v) {
    return make_uint2(pkh2(v.x, v.y), pkh2(v.z, v.w));
}

// ---- async global -> LDS, 16 B per lane (HW scatters to base + lane*16) ----
__device__ __forceinline__ void gl_lds16(const void* g, void* l) {
    __builtin_amdgcn_global_load_lds(
        (const __attribute__((address_space(1))) unsigned int*)g,
        (__attribute__((address_space(3))) unsigned int*)l,
        16, 0, 0);
}

// ===========================================================================
// MFMA GEMM common: 128x128 block, 4 waves (2x2), wave=64x64 of 16x16x32 f16
// LDS: linear [128][32] halves (64 B rows) — required by global_load_lds.
// C/D mapping (verified R1/R2): col = lane&15 (N-op), row = (lane>>4)*4+reg
// ===========================================================================
#define MFMA_PROLOG() \
    const int tid  = threadIdx.x; \
    const int w    = tid >> 6; \
    const int wm   = (w >> 1) * 64; \
    const int wn   = (w & 1) * 64; \
    const int lane = tid & 63; \
    const int q    = lane >> 4; \
    const int lr   = lane & 15; \
    float4v acc[4][4] = {};

// staging: wave w owns rows [w*32, w*32+32); 2 calls of 16 rows per operand.
// lane -> row w*32 + c*16 + (lane>>2), k-chunk (lane&3)*8 (16 B).
#define STAGE_PROLOG() \
    const int rl0 = (w << 5) + (lane >> 2); \
    const int cc  = (lane & 3) * 8; \
    unsigned short* const Aw0 = &As[w * 1024]; \
    unsigned short* const Aw1 = &As[w * 1024 + 512]; \
    unsigned short* const Bw0 = &Bs[w * 1024]; \
    unsigned short* const Bw1 = &Bs[w * 1024 + 512];

#define MFMA_COMPUTE_F16() \
    { \
        half8 afr[4], bfr[4]; \
        _Pragma("unroll") \
        for (int i = 0; i < 4; i++) \
            afr[i] = *(const half8*)&As[(wm + i * 16 + lr) * 32 + q * 8]; \
        _Pragma("unroll") \
        for (int j = 0; j < 4; j++) \
            bfr[j] = *(const half8*)&Bs[(wn + j * 16 + lr) * 32 + q * 8]; \
        _Pragma("unroll") \
        for (int i = 0; i < 4; i++) \
            _Pragma("unroll") \
            for (int j = 0; j < 4; j++) \
                acc[i][j] = __builtin_amdgcn_mfma_f32_16x16x32_f16( \
                    afr[i], bfr[j], acc[i][j], 0, 0, 0); \
    }

// ===========================================================================
// prep_all: (a) ctx -> ctxT fp16 [b][d][s] + ctx_h fp16; (b) inp/W -> fp16
// ===========================================================================
__global__ __launch_bounds__(256) void prep_all(
    const float* __restrict__ ctx, const float* __restrict__ inp,
    const float* __restrict__ W,
    unsigned short* __restrict__ ctxT, unsigned short* __restrict__ ctx_h,
    unsigned short* __restrict__ inp_h, unsigned short* __restrict__ W_h)
{
    __shared__ unsigned short Ts[64 * 68];
    const int bid = blockIdx.x;
    const int tid = threadIdx.x;
    if (bid < 3072) {               // transpose tiles: 16 s0 x 12 d0 x 16 b
        const int b   = bid / 192;
        const int rem = bid - b * 192;
        const int d0  = (rem >> 4) * 64;
        const int s0  = (rem & 15) * 64;
        const int srel = tid >> 4;              // 0..15
        const int dcol = (tid & 15) * 4;        // 0..60
#pragma unroll
        for (int r = 0; r < 4; r++) {
            const int s = srel + r * 16;
            float4 v = *(const float4*)(ctx + ((size_t)b * S_ + s0 + s) * D_ + d0 + dcol);
            Ts[(dcol + 0) * 68 + s] = f2h(v.x);
            Ts[(dcol + 1) * 68 + s] = f2h(v.y);
            Ts[(dcol + 2) * 68 + s] = f2h(v.z);
            Ts[(dcol + 3) * 68 + s] = f2h(v.w);
            *(uint2*)(ctx_h + ((size_t)b * S_ + s0 + s) * D_ + d0 + dcol) = pkh4(v);
        }
        __syncthreads();
        const int drow = tid >> 2;              // 0..63
        const int scg  = (tid & 3) * 16;        // 0..48
        unsigned short* dst = ctxT + ((size_t)b * D_ + d0 + drow) * S_ + s0 + scg;
#pragma unroll
        for (int p = 0; p < 4; p++) {
            uint2 u = *(const uint2*)&Ts[drow * 68 + scg + p * 4];
            *(uint2*)(dst + p * 4) = u;
        }
    } else {                        // fp16 precasts of inp and W
        const size_t i4 = (size_t)(bid - 3072) * 256 + tid;
        const size_t flat = i4 * 4;
        float4 v;
        unsigned short* dst;
        if (flat < NI_) {
            v = ((const float4*)inp)[i4];
            dst = inp_h + flat;
        } else {
            v = *(const float4*)(W + (flat - NI_));
            dst = W_h + (flat - NI_);
        }
        *(uint2*)dst = pkh4(v);
    }
}

// ===========================================================================
// GEMM1 (fp16 MFMA, async staging): scores = inputs @ ctx^T -> out2 [T,B,S]
// A = ctx_h rows (M = s), B = inp_h rows (N = t)
// ===========================================================================
__global__ __launch_bounds__(256) void gemm_scores_f16(
    const unsigned short* __restrict__ ctx_h,
    const unsigned short* __restrict__ inp_h,
    float* __restrict__ out2)
{
    const int b  = blockIdx.z;
    const int t0 = blockIdx.y * 128;
    const int s0 = blockIdx.x * 128;

    __shared__ __align__(16) unsigned short As[128 * 32];
    __shared__ __align__(16) unsigned short Bs[128 * 32];

    MFMA_PROLOG();
    STAGE_PROLOG();

    const unsigned short* ga0 = ctx_h + ((size_t)b * S_ + s0 + rl0) * D_ + cc;
    const unsigned short* ga1 = ga0 + (size_t)16 * D_;
    const unsigned short* gb0 = inp_h + ((size_t)b * T_ + t0 + rl0) * D_ + cc;
    const unsigned short* gb1 = gb0 + (size_t)16 * D_;

    for (int kb = 0; kb < D_; kb += 32) {
        __syncthreads();
        gl_lds16(ga0 + kb, Aw0);
        gl_lds16(ga1 + kb, Aw1);
        gl_lds16(gb0 + kb, Bw0);
        gl_lds16(gb1 + kb, Bw1);
        __syncthreads();
        MFMA_COMPUTE_F16();
    }

#pragma unroll
    for (int i = 0; i < 4; i++)
#pragma unroll
        for (int j = 0; j < 4; j++) {
            const int t = t0 + wn + j * 16 + lr;
            const int s = s0 + wm + i * 16 + q * 4;
            *(float4v*)(out2 + (size_t)t * BS_ + (size_t)b * S_ + s) = acc[i][j];
        }
}

// ===========================================================================
// softmax_rows: out2 (scores fp32) -> av_h [t][b][s] fp16
// ===========================================================================
__global__ __launch_bounds__(256) void softmax_rows(
    const float* __restrict__ scores, unsigned short* __restrict__ av_h)
{
    const int bid = blockIdx.x;
    const int b = bid & (B_ - 1);
    const int t = bid / B_;
    const float* row = scores + (size_t)t * BS_ + (size_t)b * S_;
    const int tid = threadIdx.x;

    float4 v = ((const float4*)row)[tid];
    float m = fmaxf(fmaxf(v.x, v.y), fmaxf(v.z, v.w));
#pragma unroll
    for (int off = 32; off > 0; off >>= 1) m = fmaxf(m, __shfl_xor(m, off));

    __shared__ float red[8];
    if ((tid & 63) == 0) red[tid >> 6] = m;
    __syncthreads();
    m = fmaxf(fmaxf(red[0], red[1]), fmaxf(red[2], red[3]));

    float4 e;
    e.x = __expf(v.x - m); e.y = __expf(v.y - m);
    e.z = __expf(v.z - m); e.w = __expf(v.w - m);
    float s = e.x + e.y + e.z + e.w;
#pragma unroll
    for (int off = 32; off > 0; off >>= 1) s += __shfl_xor(s, off);
    if ((tid & 63) == 0) red[4 + (tid >> 6)] = s;
    __syncthreads();
    s = (red[4] + red[5]) + (red[6] + red[7]);

    const float inv = 1.0f / s;
    e.x *= inv; e.y *= inv; e.z *= inv; e.w *= inv;
    unsigned short* orow = av_h + (size_t)t * BS_ + (size_t)b * S_;
    *(uint2*)(orow + tid * 4) = pkh4(e);
}

// ===========================================================================
// colsum_part: partial[c][b][s] = sum over t-chunk c (128 rows) of av_h
// ===========================================================================
__global__ __launch_bounds__(256) void colsum_part(
    const unsigned short* __restrict__ av_h, float* __restrict__ partial)
{
    const int b = blockIdx.y;
    const int c = blockIdx.z;
    const int s2 = blockIdx.x * 512 + threadIdx.x * 2;
    const unsigned short* p = av_h + (size_t)(c * 128) * BS_ + (size_t)b * S_ + s2;
    float s0 = 0.0f, s1 = 0.0f;
#pragma unroll 8
    for (int t = 0; t < 128; t++) {
        const unsigned u = *(const unsigned*)(p + (size_t)t * BS_);
        s0 += h2f((unsigned short)(u & 0xffff));
        s1 += h2f((unsigned short)(u >> 16));
    }
    *(float2*)(partial + ((size_t)c * B_ + b) * S_ + s2) = make_float2(s0, s1);
}

// gate[b][s] = sigmoid(colsum) / S
__global__ __launch_bounds__(256) void gate_final(
    const float* __restrict__ partial, float* __restrict__ gate)
{
    const int idx = blockIdx.x * 256 + threadIdx.x;   // b*1024 + s
    const int b = idx >> 10, s = idx & (S_ - 1);
    float sum = 0.0f;
#pragma unroll
    for (int c = 0; c < T_ / 128; c++) sum += partial[((size_t)c * B_ + b) * S_ + s];
    gate[idx] = (1.0f / (1.0f + __expf(-sum))) * (1.0f / (float)S_);
}

// av_g (out2, fp32) = f32(av_h) * gate[b][s]
__global__ __launch_bounds__(256) void av_out(
    const unsigned short* __restrict__ av_h, const float* __restrict__ gate,
    float* __restrict__ out2)
{
    const size_t i8 = ((size_t)blockIdx.x * 256 + threadIdx.x) * 8;
    const int s = (int)(i8 & (S_ - 1));
    const int b = (int)((i8 >> 10) & (B_ - 1));
    const uint4 u = *(const uint4*)(av_h + i8);
    const float4 g0 = *(const float4*)(gate + b * S_ + s);
    const float4 g1 = *(const float4*)(gate + b * S_ + s + 4);
    float4 o0 = make_float4(h2f(u.x & 0xffff) * g0.x, h2f(u.x >> 16) * g0.y,
                            h2f(u.y & 0xffff) * g0.z, h2f(u.y >> 16) * g0.w);
    float4 o1 = make_float4(h2f(u.z & 0xffff) * g1.x, h2f(u.z >> 16) * g1.y,
                            h2f(u.w & 0xffff) * g1.z, h2f(u.w >> 16) * g1.w);
    *(float4*)(out2 + i8) = o0;
    *(float4*)(out2 + i8 + 4) = o1;
}

// ctxT[b][d][s] *= gate[b][s]  (in place) — folds gate into GEMM2's A operand
__global__ __launch_bounds__(256) void scale_ctxT(
    unsigned short* __restrict__ ctxT, const float* __restrict__ gate)
{
    const int b = blockIdx.y;
    const int d = blockIdx.x * 2 + (threadIdx.x >> 7);
    const int s = (threadIdx.x & 127) * 8;
    unsigned short* p = ctxT + ((size_t)b * D_ + d) * S_ + s;
    const uint4 u = *(const uint4*)p;
    const float4 g0 = *(const float4*)(gate + b * S_ + s);
    const float4 g1 = *(const float4*)(gate + b * S_ + s + 4);
    uint4 o;
    o.x = pkh2(h2f(u.x & 0xffff) * g0.x, h2f(u.x >> 16) * g0.y);
    o.y = pkh2(h2f(u.y & 0xffff) * g0.z, h2f(u.y >> 16) * g0.w);
    o.z = pkh2(h2f(u.z & 0xffff) * g1.x, h2f(u.z >> 16) * g1.y);
    o.w = pkh2(h2f(u.w & 0xffff) * g1.z, h2f(u.w >> 16) * g1.w);
    *(uint4*)p = o;
}

// ===========================================================================
// GEMM2 (fp16, async staging): c_h[b,t,d] = f16( (av @ ctxT_g) * ws + bs )
// A = ctxT_g rows (M = d), B = av_h rows (N = t)
// ===========================================================================
__global__ __launch_bounds__(256) void gemm_ctx_f16(
    const unsigned short* __restrict__ ctxT, const unsigned short* __restrict__ av_h,
    const float* __restrict__ w_scale, const float* __restrict__ b_scale,
    unsigned short* __restrict__ c_h)
{
    const int b  = blockIdx.z;
    const int d0 = blockIdx.y * 128;
    const int t0 = blockIdx.x * 128;

    __shared__ __align__(16) unsigned short As[128 * 32];
    __shared__ __align__(16) unsigned short Bs[128 * 32];

    MFMA_PROLOG();
    STAGE_PROLOG();

    const unsigned short* ga0 = ctxT + ((size_t)b * D_ + d0 + rl0) * S_ + cc;
    const unsigned short* ga1 = ga0 + (size_t)16 * S_;
    const unsigned short* gb0 = av_h + (size_t)(t0 + rl0) * BS_ + (size_t)b * S_ + cc;
    const unsigned short* gb1 = gb0 + (size_t)16 * BS_;

    for (int sb = 0; sb < S_; sb += 32) {
        __syncthreads();
        gl_lds16(ga0 + sb, Aw0);
        gl_lds16(ga1 + sb, Aw1);
        gl_lds16(gb0 + sb, Bw0);
        gl_lds16(gb1 + sb, Bw1);
        __syncthreads();
        MFMA_COMPUTE_F16();
    }

    const float wsc = w_scale[0], bsc = b_scale[0];
#pragma unroll
    for (int i = 0; i < 4; i++)
#pragma unroll
        for (int j = 0; j < 4; j++) {
            const int d = d0 + wm + i * 16 + q * 4;
            const int t = t0 + wn + j * 16 + lr;
            uint2 o;
            o.x = pkh2(acc[i][j][0] * wsc + bsc, acc[i][j][1] * wsc + bsc);
            o.y = pkh2(acc[i][j][2] * wsc + bsc, acc[i][j][3] * wsc + bsc);
            *(uint2*)(c_h + ((size_t)b * T_ + t) * D_ + d) = o;
        }
}

// ===========================================================================
// GEMM3 (fp16, async staging): h = prelu(concat(c_h, inp_h) @ W_h^T + bias)
// A = W_h rows (M = d), B = concat rows (N = n = b*T+t)
// ===========================================================================
__global__ __launch_bounds__(256) void gemm_out_f16(
    const unsigned short* __restrict__ c_h, const unsigned short* __restrict__ inp_h,
    const unsigned short* __restrict__ W_h, const float* __restrict__ bias,
    const float* __restrict__ prelu_a, float* __restrict__ out0)
{
    const int n0 = blockIdx.x * 128;
    const int d0 = blockIdx.y * 128;

    __shared__ __align__(16) unsigned short As[128 * 32];
    __shared__ __align__(16) unsigned short Bs[128 * 32];

    MFMA_PROLOG();
    STAGE_PROLOG();

    const unsigned short* ga0  = W_h + (size_t)(d0 + rl0) * K3_ + cc;
    const unsigned short* ga1  = ga0 + (size_t)16 * K3_;
    const unsigned short* gbc0 = c_h + (size_t)(n0 + rl0) * D_ + cc;
    const unsigned short* gbi0 = inp_h + (size_t)(n0 + rl0) * D_ + cc;

    for (int kb = 0; kb < K3_; kb += 32) {
        const unsigned short* gb0 = (kb < D_) ? gbc0 + kb : gbi0 + (kb - D_);
        const unsigned short* gb1 = gb0 + (size_t)16 * D_;
        __syncthreads();
        gl_lds16(ga0 + kb, Aw0);
        gl_lds16(ga1 + kb, Aw1);
        gl_lds16(gb0, Bw0);
        gl_lds16(gb1, Bw1);
        __syncthreads();
        MFMA_COMPUTE_F16();
    }

    const float pa = prelu_a[0];
#pragma unroll
    for (int i = 0; i < 4; i++) {
        const int d = d0 + wm + i * 16 + q * 4;
        const float4 bz = *(const float4*)(bias + d);
#pragma unroll
        for (int j = 0; j < 4; j++) {
            const int n = n0 + wn + j * 16 + lr;
            const int bb = n >> 10;
            const int t = n & (T_ - 1);
            float4 h;
            h.x = acc[i][j][0] + bz.x;
            h.y = acc[i][j][1] + bz.y;
            h.z = acc[i][j][2] + bz.z;
            h.w = acc[i][j][3] + bz.w;
            h.x = h.x >= 0.0f ? h.x : pa * h.x;
            h.y = h.y >= 0.0f ? h.y : pa * h.y;
            h.z = h.z >= 0.0f ? h.z : pa * h.z;
            h.w = h.w >= 0.0f ? h.w : pa * h.w;
            *(float4*)(out0 + (size_t)t * BD_ + (size_t)bb * D_ + d) = h;
        }
    }
}

// ===========================================================================
extern "C" void kernel_launch(void* const* d_in, const int* in_sizes, int n_in,
                              void* d_out, int out_size, void* d_ws, size_t ws_size,
                              hipStream_t stream)
{
    const float* inputs  = (const float*)d_in[0];   // [B,T,768]
    const float* context = (const float*)d_in[1];   // [B,S,768]
    const float* W_out   = (const float*)d_in[2];   // [768,1536]
    const float* b_out   = (const float*)d_in[3];   // [768]
    const float* w_scale = (const float*)d_in[4];
    const float* b_scale = (const float*)d_in[5];
    const float* prelu_a = (const float*)d_in[6];

    float* out0 = (float*)d_out;                          // [T,B,768]
    float* out2 = out0 + (size_t)T_ * B_ * D_;            // [T,B,S] (scores -> av_g)

    // ws layout (fp16 regions then fp32 regions):
    unsigned short* c_h   = (unsigned short*)d_ws;                 // B*T*D
    unsigned short* ctxT  = c_h   + (size_t)B_ * T_ * D_;          // B*D*S
    unsigned short* av_h  = ctxT  + (size_t)B_ * D_ * S_;          // T*B*S
    unsigned short* inp_h = av_h  + (size_t)T_ * B_ * S_;          // B*T*D
    unsigned short* W_h   = inp_h + (size_t)B_ * T_ * D_;          // D*K3
    float* gate    = (float*)(W_h + (size_t)NW_);                  // B*S
    float* partial = gate + (size_t)B_ * S_;                       // 8*B*S

    // 0. merged precasts: ctx->ctxT+ctx_h (staged in c_h region; lifetimes
    //    disjoint: gemm2 writes c_h only after gemm1 consumed ctx_h), inp/W->fp16
    prep_all<<<3072 + (NI_ + NW_) / 4 / 256, 256, 0, stream>>>(
        context, inputs, W_out, ctxT, c_h, inp_h, W_h);
    // 1. scores -> out2 (fp16 MFMA, async global->LDS staging)
    gemm_scores_f16<<<dim3(S_ / 128, T_ / 128, B_), 256, 0, stream>>>(
        c_h /*ctx_h*/, inp_h, out2);
    // 2. softmax: out2 -> av_h (fp16)
    softmax_rows<<<B_ * T_, 256, 0, stream>>>(out2, av_h);
    // 3. column partial sums over t
    colsum_part<<<dim3(S_ / 512, B_, T_ / 128), 256, 0, stream>>>(av_h, partial);
    // 4. gate = sigmoid(colsum)/S
    gate_final<<<(B_ * S_) / 256, 256, 0, stream>>>(partial, gate);
    // 5. av_g -> out2 (final output 1)
    av_out<<<(int)(((size_t)T_ * B_ * S_ / 8) / 256), 256, 0, stream>>>(av_h, gate, out2);
    // 6. fold gate into ctxT (in place)
    scale_ctxT<<<dim3(D_ / 2, B_), 256, 0, stream>>>(ctxT, gate);
    // 7. c_h = f16((av @ ctxT_g) * ws + bs)   [fp16 MFMA, async staging]
    gemm_ctx_f16<<<dim3(T_ / 128, D_ / 128, B_), 256, 0, stream>>>(
        ctxT, av_h, w_scale, b_scale, c_h);
    // 8. h = prelu(concat @ W^T + b) -> out0   [fp16 MFMA, async staging]
    gemm_out_f16<<<dim3((B_ * T_) / 128, D_ / 128), 256, 0, stream>>>(
        c_h, inp_h, W_h, b_out, prelu_a, out0);
}

// Round 4
// 384.135 us; speedup vs baseline: 2.0257x; 1.0187x over previous
//
#include <hip/hip_runtime.h>

#define B_ 16
#define T_ 1024
#define S_ 1024
#define D_ 768      // ENC == DEC
#define K3_ 1536    // D_ + D_
#define BS_ (B_ * S_)   // 16384
#define BD_ (B_ * D_)   // 12288
#define NI_ (B_ * T_ * D_)      // 12582912 (inp elems)
#define NW_ (D_ * K3_)          // 1179648  (W elems)

typedef __attribute__((ext_vector_type(8))) _Float16 half8;
typedef __attribute__((ext_vector_type(4))) float float4v;

// ---- fp32 <-> fp16 helpers ----
__device__ __forceinline__ unsigned short f2h(float x) {
    return __builtin_bit_cast(unsigned short, (_Float16)x);
}
__device__ __forceinline__ float h2f(unsigned short u) {
    return (float)__builtin_bit_cast(_Float16, u);
}
__device__ __forceinline__ unsigned pkh2(float a, float b) {
    return (unsigned)f2h(a) | ((unsigned)f2h(b) << 16);
}
__device__ __forceinline__ uint2 pkh4(const float4 v) {
    return make_uint2(pkh2(v.x, v.y), pkh2(v.z, v.w));
}

// ---- async global -> LDS, 16 B per lane (HW scatters to base + lane*16) ----
__device__ __forceinline__ void gl_lds16(const void* g, void* l) {
    __builtin_amdgcn_global_load_lds(
        (const __attribute__((address_space(1))) unsigned int*)g,
        (__attribute__((address_space(3))) unsigned int*)l,
        16, 0, 0);
}

// ===========================================================================
// MFMA GEMM common: 128x128 block, 4 waves (2x2), wave=64x64 of 16x16x32 f16
// LDS: double-buffered linear [2][128][32] halves (global_load_lds layout).
// 2-phase K-loop: STAGE(next) -> COMPUTE(cur) -> __syncthreads (1 barrier/step)
// C/D mapping (verified R1/R2): col = lane&15 (N-op), row = (lane>>4)*4+reg
// ===========================================================================
#define MFMA_PROLOG() \
    const int tid  = threadIdx.x; \
    const int w    = tid >> 6; \
    const int wm   = (w >> 1) * 64; \
    const int wn   = (w & 1) * 64; \
    const int lane = tid & 63; \
    const int q    = lane >> 4; \
    const int lr   = lane & 15; \
    float4v acc[4][4] = {};

// staging: wave w owns rows [w*32, w*32+32); 2 calls of 16 rows per operand.
// lane -> row w*32 + c*16 + (lane>>2), k-chunk (lane&3)*8 (16 B).
#define STAGE_PROLOG() \
    const int rl0 = (w << 5) + (lane >> 2); \
    const int cc  = (lane & 3) * 8; \
    const int wb  = w * 1024;

#define MFMA_COMPUTE_F16(AS, BS) \
    { \
        half8 afr[4], bfr[4]; \
        _Pragma("unroll") \
        for (int i = 0; i < 4; i++) \
            afr[i] = *(const half8*)&(AS)[(wm + i * 16 + lr) * 32 + q * 8]; \
        _Pragma("unroll") \
        for (int j = 0; j < 4; j++) \
            bfr[j] = *(const half8*)&(BS)[(wn + j * 16 + lr) * 32 + q * 8]; \
        _Pragma("unroll") \
        for (int i = 0; i < 4; i++) \
            _Pragma("unroll") \
            for (int j = 0; j < 4; j++) \
                acc[i][j] = __builtin_amdgcn_mfma_f32_16x16x32_f16( \
                    afr[i], bfr[j], acc[i][j], 0, 0, 0); \
    }

// ===========================================================================
// prep_all: (a) ctx -> ctxT fp16 [b][d][s] + ctx_h fp16; (b) inp/W -> fp16
// ===========================================================================
__global__ __launch_bounds__(256) void prep_all(
    const float* __restrict__ ctx, const float* __restrict__ inp,
    const float* __restrict__ W,
    unsigned short* __restrict__ ctxT, unsigned short* __restrict__ ctx_h,
    unsigned short* __restrict__ inp_h, unsigned short* __restrict__ W_h)
{
    __shared__ unsigned short Ts[64 * 68];
    const int bid = blockIdx.x;
    const int tid = threadIdx.x;
    if (bid < 3072) {               // transpose tiles: 16 s0 x 12 d0 x 16 b
        const int b   = bid / 192;
        const int rem = bid - b * 192;
        const int d0  = (rem >> 4) * 64;
        const int s0  = (rem & 15) * 64;
        const int srel = tid >> 4;              // 0..15
        const int dcol = (tid & 15) * 4;        // 0..60
#pragma unroll
        for (int r = 0; r < 4; r++) {
            const int s = srel + r * 16;
            float4 v = *(const float4*)(ctx + ((size_t)b * S_ + s0 + s) * D_ + d0 + dcol);
            Ts[(dcol + 0) * 68 + s] = f2h(v.x);
            Ts[(dcol + 1) * 68 + s] = f2h(v.y);
            Ts[(dcol + 2) * 68 + s] = f2h(v.z);
            Ts[(dcol + 3) * 68 + s] = f2h(v.w);
            *(uint2*)(ctx_h + ((size_t)b * S_ + s0 + s) * D_ + d0 + dcol) = pkh4(v);
        }
        __syncthreads();
        const int drow = tid >> 2;              // 0..63
        const int scg  = (tid & 3) * 16;        // 0..48
        unsigned short* dst = ctxT + ((size_t)b * D_ + d0 + drow) * S_ + s0 + scg;
#pragma unroll
        for (int p = 0; p < 4; p++) {
            uint2 u = *(const uint2*)&Ts[drow * 68 + scg + p * 4];
            *(uint2*)(dst + p * 4) = u;
        }
    } else {                        // fp16 precasts of inp and W
        const size_t i4 = (size_t)(bid - 3072) * 256 + tid;
        const size_t flat = i4 * 4;
        float4 v;
        unsigned short* dst;
        if (flat < NI_) {
            v = ((const float4*)inp)[i4];
            dst = inp_h + flat;
        } else {
            v = *(const float4*)(W + (flat - NI_));
            dst = W_h + (flat - NI_);
        }
        *(uint2*)dst = pkh4(v);
    }
}

// ===========================================================================
// GEMM1 (fp16 MFMA, dbuf async staging): scores = inputs @ ctx^T -> out2
// A = ctx_h rows (M = s), B = inp_h rows (N = t). XCD-swizzled grid (1024 wg).
// ===========================================================================
__global__ __launch_bounds__(256) void gemm_scores_f16(
    const unsigned short* __restrict__ ctx_h,
    const unsigned short* __restrict__ inp_h,
    float* __restrict__ out2)
{
    // bijective XCD swizzle: 128 consecutive work-ids per XCD (2 batches/XCD)
    const int hwid = blockIdx.x + (blockIdx.y << 3) + (blockIdx.z << 6);
    const int wk   = (hwid & 7) * 128 + (hwid >> 3);
    const int b  = wk >> 6;
    const int t0 = ((wk >> 3) & 7) * 128;
    const int s0 = (wk & 7) * 128;

    __shared__ __align__(16) unsigned short As[2][128 * 32];
    __shared__ __align__(16) unsigned short Bs[2][128 * 32];

    MFMA_PROLOG();
    STAGE_PROLOG();

    const unsigned short* ga0 = ctx_h + ((size_t)b * S_ + s0 + rl0) * D_ + cc;
    const unsigned short* ga1 = ga0 + (size_t)16 * D_;
    const unsigned short* gb0 = inp_h + ((size_t)b * T_ + t0 + rl0) * D_ + cc;
    const unsigned short* gb1 = gb0 + (size_t)16 * D_;

    gl_lds16(ga0, &As[0][wb]);
    gl_lds16(ga1, &As[0][wb + 512]);
    gl_lds16(gb0, &Bs[0][wb]);
    gl_lds16(gb1, &Bs[0][wb + 512]);
    __syncthreads();

    int cur = 0;
    for (int kb = 32; kb < D_; kb += 32) {
        const int nxt = cur ^ 1;
        gl_lds16(ga0 + kb, &As[nxt][wb]);
        gl_lds16(ga1 + kb, &As[nxt][wb + 512]);
        gl_lds16(gb0 + kb, &Bs[nxt][wb]);
        gl_lds16(gb1 + kb, &Bs[nxt][wb + 512]);
        MFMA_COMPUTE_F16(As[cur], Bs[cur]);
        __syncthreads();
        cur = nxt;
    }
    MFMA_COMPUTE_F16(As[cur], Bs[cur]);

#pragma unroll
    for (int i = 0; i < 4; i++)
#pragma unroll
        for (int j = 0; j < 4; j++) {
            const int t = t0 + wn + j * 16 + lr;
            const int s = s0 + wm + i * 16 + q * 4;
            *(float4v*)(out2 + (size_t)t * BS_ + (size_t)b * S_ + s) = acc[i][j];
        }
}

// ===========================================================================
// softmax_rows: out2 (scores fp32) -> av_h [t][b][s] fp16
// ===========================================================================
__global__ __launch_bounds__(256) void softmax_rows(
    const float* __restrict__ scores, unsigned short* __restrict__ av_h)
{
    const int bid = blockIdx.x;
    const int b = bid & (B_ - 1);
    const int t = bid / B_;
    const float* row = scores + (size_t)t * BS_ + (size_t)b * S_;
    const int tid = threadIdx.x;

    float4 v = ((const float4*)row)[tid];
    float m = fmaxf(fmaxf(v.x, v.y), fmaxf(v.z, v.w));
#pragma unroll
    for (int off = 32; off > 0; off >>= 1) m = fmaxf(m, __shfl_xor(m, off));

    __shared__ float red[8];
    if ((tid & 63) == 0) red[tid >> 6] = m;
    __syncthreads();
    m = fmaxf(fmaxf(red[0], red[1]), fmaxf(red[2], red[3]));

    float4 e;
    e.x = __expf(v.x - m); e.y = __expf(v.y - m);
    e.z = __expf(v.z - m); e.w = __expf(v.w - m);
    float s = e.x + e.y + e.z + e.w;
#pragma unroll
    for (int off = 32; off > 0; off >>= 1) s += __shfl_xor(s, off);
    if ((tid & 63) == 0) red[4 + (tid >> 6)] = s;
    __syncthreads();
    s = (red[4] + red[5]) + (red[6] + red[7]);

    const float inv = 1.0f / s;
    e.x *= inv; e.y *= inv; e.z *= inv; e.w *= inv;
    unsigned short* orow = av_h + (size_t)t * BS_ + (size_t)b * S_;
    *(uint2*)(orow + tid * 4) = pkh4(e);
}

// ===========================================================================
// colsum_part: partial[c][b][s] = sum over t-chunk c (128 rows) of av_h
// ===========================================================================
__global__ __launch_bounds__(256) void colsum_part(
    const unsigned short* __restrict__ av_h, float* __restrict__ partial)
{
    const int b = blockIdx.y;
    const int c = blockIdx.z;
    const int s2 = blockIdx.x * 512 + threadIdx.x * 2;
    const unsigned short* p = av_h + (size_t)(c * 128) * BS_ + (size_t)b * S_ + s2;
    float s0 = 0.0f, s1 = 0.0f;
#pragma unroll 8
    for (int t = 0; t < 128; t++) {
        const unsigned u = *(const unsigned*)(p + (size_t)t * BS_);
        s0 += h2f((unsigned short)(u & 0xffff));
        s1 += h2f((unsigned short)(u >> 16));
    }
    *(float2*)(partial + ((size_t)c * B_ + b) * S_ + s2) = make_float2(s0, s1);
}

// gate[b][s] = sigmoid(colsum)   (1/S folded into av_out and gemm2 epilogue)
__global__ __launch_bounds__(256) void gate_final(
    const float* __restrict__ partial, float* __restrict__ gate)
{
    const int idx = blockIdx.x * 256 + threadIdx.x;   // b*1024 + s
    const int b = idx >> 10, s = idx & (S_ - 1);
    float sum = 0.0f;
#pragma unroll
    for (int c = 0; c < T_ / 128; c++) sum += partial[((size_t)c * B_ + b) * S_ + s];
    gate[idx] = 1.0f / (1.0f + __expf(-sum));
}

// av_out: out2 (fp32) = av * gate / S   (final output 1)
//         av_h (fp16, in place) = f16(av * gate)   -> gemm2's B operand
__global__ __launch_bounds__(256) void av_out(
    unsigned short* __restrict__ av_h, const float* __restrict__ gate,
    float* __restrict__ out2)
{
    const size_t i8 = ((size_t)blockIdx.x * 256 + threadIdx.x) * 8;
    const int s = (int)(i8 & (S_ - 1));
    const int b = (int)((i8 >> 10) & (B_ - 1));
    const uint4 u = *(const uint4*)(av_h + i8);
    const float4 g0 = *(const float4*)(gate + b * S_ + s);
    const float4 g1 = *(const float4*)(gate + b * S_ + s + 4);
    float a0 = h2f(u.x & 0xffff) * g0.x, a1 = h2f(u.x >> 16) * g0.y;
    float a2 = h2f(u.y & 0xffff) * g0.z, a3 = h2f(u.y >> 16) * g0.w;
    float a4 = h2f(u.z & 0xffff) * g1.x, a5 = h2f(u.z >> 16) * g1.y;
    float a6 = h2f(u.w & 0xffff) * g1.z, a7 = h2f(u.w >> 16) * g1.w;
    const float is = 1.0f / (float)S_;
    *(float4*)(out2 + i8)     = make_float4(a0 * is, a1 * is, a2 * is, a3 * is);
    *(float4*)(out2 + i8 + 4) = make_float4(a4 * is, a5 * is, a6 * is, a7 * is);
    uint4 o;
    o.x = pkh2(a0, a1); o.y = pkh2(a2, a3);
    o.z = pkh2(a4, a5); o.w = pkh2(a6, a7);
    *(uint4*)(av_h + i8) = o;
}

// ===========================================================================
// GEMM2 (fp16, dbuf): c_h[b,t,d] = f16( (av_g' @ ctxT) * ws/S + bs )
// A = ctxT rows (M = d), B = av_h rows (= av*gate, N = t). XCD swizzle (768).
// ===========================================================================
__global__ __launch_bounds__(256) void gemm_ctx_f16(
    const unsigned short* __restrict__ ctxT, const unsigned short* __restrict__ av_h,
    const float* __restrict__ w_scale, const float* __restrict__ b_scale,
    unsigned short* __restrict__ c_h)
{
    const int hwid = blockIdx.x + blockIdx.y * 8 + blockIdx.z * 48;
    const int wk   = (hwid & 7) * 96 + (hwid >> 3);
    const int t0 = (wk % 8) * 128;
    const int d0 = ((wk / 8) % 6) * 128;
    const int b  = wk / 48;

    __shared__ __align__(16) unsigned short As[2][128 * 32];
    __shared__ __align__(16) unsigned short Bs[2][128 * 32];

    MFMA_PROLOG();
    STAGE_PROLOG();

    const unsigned short* ga0 = ctxT + ((size_t)b * D_ + d0 + rl0) * S_ + cc;
    const unsigned short* ga1 = ga0 + (size_t)16 * S_;
    const unsigned short* gb0 = av_h + (size_t)(t0 + rl0) * BS_ + (size_t)b * S_ + cc;
    const unsigned short* gb1 = gb0 + (size_t)16 * BS_;

    gl_lds16(ga0, &As[0][wb]);
    gl_lds16(ga1, &As[0][wb + 512]);
    gl_lds16(gb0, &Bs[0][wb]);
    gl_lds16(gb1, &Bs[0][wb + 512]);
    __syncthreads();

    int cur = 0;
    for (int sb = 32; sb < S_; sb += 32) {
        const int nxt = cur ^ 1;
        gl_lds16(ga0 + sb, &As[nxt][wb]);
        gl_lds16(ga1 + sb, &As[nxt][wb + 512]);
        gl_lds16(gb0 + sb, &Bs[nxt][wb]);
        gl_lds16(gb1 + sb, &Bs[nxt][wb + 512]);
        MFMA_COMPUTE_F16(As[cur], Bs[cur]);
        __syncthreads();
        cur = nxt;
    }
    MFMA_COMPUTE_F16(As[cur], Bs[cur]);

    const float wsc = w_scale[0] * (1.0f / (float)S_);
    const float bsc = b_scale[0];
#pragma unroll
    for (int i = 0; i < 4; i++)
#pragma unroll
        for (int j = 0; j < 4; j++) {
            const int d = d0 + wm + i * 16 + q * 4;
            const int t = t0 + wn + j * 16 + lr;
            uint2 o;
            o.x = pkh2(acc[i][j][0] * wsc + bsc, acc[i][j][1] * wsc + bsc);
            o.y = pkh2(acc[i][j][2] * wsc + bsc, acc[i][j][3] * wsc + bsc);
            *(uint2*)(c_h + ((size_t)b * T_ + t) * D_ + d) = o;
        }
}

// ===========================================================================
// GEMM3 (fp16, dbuf): h = prelu(concat(c_h, inp_h) @ W_h^T + bias) -> out0
// A = W_h rows (M = d), B = concat rows (N = n). grid (6, 128), XCD swizzle.
// ===========================================================================
__global__ __launch_bounds__(256) void gemm_out_f16(
    const unsigned short* __restrict__ c_h, const unsigned short* __restrict__ inp_h,
    const unsigned short* __restrict__ W_h, const float* __restrict__ bias,
    const float* __restrict__ prelu_a, float* __restrict__ out0)
{
    const int hwid = blockIdx.x + blockIdx.y * 6;
    const int wk   = (hwid & 7) * 96 + (hwid >> 3);
    const int d0 = (wk % 6) * 128;
    const int n0 = (wk / 6) * 128;

    __shared__ __align__(16) unsigned short As[2][128 * 32];
    __shared__ __align__(16) unsigned short Bs[2][128 * 32];

    MFMA_PROLOG();
    STAGE_PROLOG();

    const unsigned short* ga0  = W_h + (size_t)(d0 + rl0) * K3_ + cc;
    const unsigned short* ga1  = ga0 + (size_t)16 * K3_;
    const unsigned short* gbc0 = c_h + (size_t)(n0 + rl0) * D_ + cc;
    const unsigned short* gbi0 = inp_h + (size_t)(n0 + rl0) * D_ + cc;

    gl_lds16(ga0, &As[0][wb]);
    gl_lds16(ga1, &As[0][wb + 512]);
    gl_lds16(gbc0, &Bs[0][wb]);
    gl_lds16(gbc0 + (size_t)16 * D_, &Bs[0][wb + 512]);
    __syncthreads();

    int cur = 0;
    for (int kb = 32; kb < K3_; kb += 32) {
        const int nxt = cur ^ 1;
        const unsigned short* gb0 = (kb < D_) ? gbc0 + kb : gbi0 + (kb - D_);
        gl_lds16(ga0 + kb, &As[nxt][wb]);
        gl_lds16(ga1 + kb, &As[nxt][wb + 512]);
        gl_lds16(gb0, &Bs[nxt][wb]);
        gl_lds16(gb0 + (size_t)16 * D_, &Bs[nxt][wb + 512]);
        MFMA_COMPUTE_F16(As[cur], Bs[cur]);
        __syncthreads();
        cur = nxt;
    }
    MFMA_COMPUTE_F16(As[cur], Bs[cur]);

    const float pa = prelu_a[0];
#pragma unroll
    for (int i = 0; i < 4; i++) {
        const int d = d0 + wm + i * 16 + q * 4;
        const float4 bz = *(const float4*)(bias + d);
#pragma unroll
        for (int j = 0; j < 4; j++) {
            const int n = n0 + wn + j * 16 + lr;
            const int bb = n >> 10;
            const int t = n & (T_ - 1);
            float4 h;
            h.x = acc[i][j][0] + bz.x;
            h.y = acc[i][j][1] + bz.y;
            h.z = acc[i][j][2] + bz.z;
            h.w = acc[i][j][3] + bz.w;
            h.x = h.x >= 0.0f ? h.x : pa * h.x;
            h.y = h.y >= 0.0f ? h.y : pa * h.y;
            h.z = h.z >= 0.0f ? h.z : pa * h.z;
            h.w = h.w >= 0.0f ? h.w : pa * h.w;
            *(float4*)(out0 + (size_t)t * BD_ + (size_t)bb * D_ + d) = h;
        }
    }
}

// ===========================================================================
extern "C" void kernel_launch(void* const* d_in, const int* in_sizes, int n_in,
                              void* d_out, int out_size, void* d_ws, size_t ws_size,
                              hipStream_t stream)
{
    const float* inputs  = (const float*)d_in[0];   // [B,T,768]
    const float* context = (const float*)d_in[1];   // [B,S,768]
    const float* W_out   = (const float*)d_in[2];   // [768,1536]
    const float* b_out   = (const float*)d_in[3];   // [768]
    const float* w_scale = (const float*)d_in[4];
    const float* b_scale = (const float*)d_in[5];
    const float* prelu_a = (const float*)d_in[6];

    float* out0 = (float*)d_out;                          // [T,B,768]
    float* out2 = out0 + (size_t)T_ * B_ * D_;            // [T,B,S] (scores -> av_g)

    // ws layout (fp16 regions then fp32 regions):
    unsigned short* c_h   = (unsigned short*)d_ws;                 // B*T*D
    unsigned short* ctxT  = c_h   + (size_t)B_ * T_ * D_;          // B*D*S
    unsigned short* av_h  = ctxT  + (size_t)B_ * D_ * S_;          // T*B*S
    unsigned short* inp_h = av_h  + (size_t)T_ * B_ * S_;          // B*T*D
    unsigned short* W_h   = inp_h + (size_t)B_ * T_ * D_;          // D*K3
    float* gate    = (float*)(W_h + (size_t)NW_);                  // B*S
    float* partial = gate + (size_t)B_ * S_;                       // 8*B*S

    // 0. merged precasts: ctx->ctxT+ctx_h (staged in c_h region; lifetimes
    //    disjoint: gemm2 writes c_h only after gemm1 consumed ctx_h), inp/W->fp16
    prep_all<<<3072 + (NI_ + NW_) / 4 / 256, 256, 0, stream>>>(
        context, inputs, W_out, ctxT, c_h, inp_h, W_h);
    // 1. scores -> out2 (fp16 MFMA, dbuf async staging, XCD swizzle)
    gemm_scores_f16<<<dim3(S_ / 128, T_ / 128, B_), 256, 0, stream>>>(
        c_h /*ctx_h*/, inp_h, out2);
    // 2. softmax: out2 -> av_h (fp16)
    softmax_rows<<<B_ * T_, 256, 0, stream>>>(out2, av_h);
    // 3. column partial sums over t
    colsum_part<<<dim3(S_ / 512, B_, T_ / 128), 256, 0, stream>>>(av_h, partial);
    // 4. gate = sigmoid(colsum)
    gate_final<<<(B_ * S_) / 256, 256, 0, stream>>>(partial, gate);
    // 5. out2 = av*gate/S (output 1); av_h *= gate in place (gemm2 operand)
    av_out<<<(int)(((size_t)T_ * B_ * S_ / 8) / 256), 256, 0, stream>>>(
        av_h, gate, out2);
    // 6. c_h = f16((av_g' @ ctxT) * ws/S + bs)   [fp16 MFMA, dbuf]
    gemm_ctx_f16<<<dim3(T_ / 128, D_ / 128, B_), 256, 0, stream>>>(
        ctxT, av_h, w_scale, b_scale, c_h);
    // 7. h = prelu(concat @ W^T + b) -> out0   [fp16 MFMA, dbuf]
    gemm_out_f16<<<dim3(D_ / 128, (B_ * T_) / 128), 256, 0, stream>>>(
        c_h, inp_h, W_h, b_out, prelu_a, out0);
}